// Round 1
// baseline (1497.001 us; speedup 1.0000x reference)
//
#include <hip/hip_runtime.h>
#include <hip/hip_bf16.h>

#define B_   8
#define C_   512
#define HW_  4096
#define M_   1024
#define N_   3072
#define EPS_ 1e-8f

#define KCH   16
#define NTILE 512

// ---------------- K1: per-column inverse norms (all 4096 columns) ----------
__global__ void k_norms(const float* __restrict__ x, float* __restrict__ inv_all) {
    int blk = blockIdx.x;            // 256 blocks = 8 b * 32 chunks
    int b = blk >> 5;
    int chunk = blk & 31;
    int hw = chunk * 128 + threadIdx.x;   // 128 threads
    const float* xb = x + (size_t)b * C_ * HW_;
    float acc = 0.f;
#pragma unroll 8
    for (int c = 0; c < C_; ++c) {
        float v = xb[(size_t)c * HW_ + hw];
        acc = fmaf(v, v, acc);
    }
    inv_all[b * HW_ + hw] = 1.0f / (sqrtf(acc) + EPS_);
}

// ---------------- K2: cos-sim GEMM + per-row top-2 ------------------------
// grid = 512 blocks: b(8) x mtile(32, 32 rows each) x nsplit(2, 1536 each)
// block = 256 threads = 4 tm x 64 tn ; microtile 8m x 8n ; tile 32m x 512n
__global__ __launch_bounds__(256, 2) void k_cos(
    const float* __restrict__ x, const int* __restrict__ nm_idx,
    const int* __restrict__ m_idx, const float* __restrict__ inv_all,
    float* __restrict__ pmax, int* __restrict__ pidx)
{
    __shared__ float As[KCH][32];
    __shared__ float Bs[KCH][NTILE];
    __shared__ int   nsp[NTILE];
    __shared__ float invc[NTILE];
    __shared__ int   ps[32];
    __shared__ float invm[32];

    int blk = blockIdx.x;
    int b     = blk >> 6;
    int mt    = (blk >> 1) & 31;
    int split = blk & 1;
    int m0 = mt * 32;
    int t  = threadIdx.x;
    int tn = t & 63;
    int tm = t >> 6;

    const float* xb   = x + (size_t)b * C_ * HW_;
    const float* invb = inv_all + b * HW_;

    if (t < 32) {
        int p = m_idx[m0 + t];
        ps[t] = p;
        invm[t] = invb[p];
    }

    float v1[8], v2[8]; int i1[8], i2[8];
#pragma unroll
    for (int mi = 0; mi < 8; ++mi) {
        v1[mi] = -3.402823466e38f; v2[mi] = -3.402823466e38f;
        i1[mi] = 0x7fffffff;       i2[mi] = 0x7fffffff;
    }

    int nbase = split * 1536;
    for (int nt = 0; nt < 1536; nt += NTILE) {
        __syncthreads();   // protect nsp/invc (and ps/invm on first pass)
        {
            int j = t;
            int p = nm_idx[nbase + nt + j];
            nsp[j] = p; invc[j] = invb[p];
            j = t + 256;
            p = nm_idx[nbase + nt + j];
            nsp[j] = p; invc[j] = invb[p];
        }
        __syncthreads();

        float acc[8][8];
#pragma unroll
        for (int a = 0; a < 8; ++a)
#pragma unroll
            for (int q = 0; q < 8; ++q) acc[a][q] = 0.f;

        for (int k0 = 0; k0 < C_; k0 += KCH) {
            // stage A: 16k x 32m
            {
                int idx = t;
                int kk = idx >> 5, i = idx & 31;
                As[kk][i] = xb[(size_t)(k0 + kk) * HW_ + ps[i]];
                idx = t + 256; kk = idx >> 5; i = idx & 31;
                As[kk][i] = xb[(size_t)(k0 + kk) * HW_ + ps[i]];
            }
            // stage B: 16k x 512n
#pragma unroll
            for (int rep = 0; rep < 32; ++rep) {
                int idx = rep * 256 + t;
                int kk = idx >> 9, j = idx & 511;
                Bs[kk][j] = xb[(size_t)(k0 + kk) * HW_ + nsp[j]];
            }
            __syncthreads();
#pragma unroll
            for (int kk = 0; kk < KCH; ++kk) {
                float a[8], bb[8];
                *(float4*)&a[0]  = *(const float4*)&As[kk][tm * 8];
                *(float4*)&a[4]  = *(const float4*)&As[kk][tm * 8 + 4];
                *(float4*)&bb[0] = *(const float4*)&Bs[kk][tn * 4];
                *(float4*)&bb[4] = *(const float4*)&Bs[kk][256 + tn * 4];
#pragma unroll
                for (int mi = 0; mi < 8; ++mi)
#pragma unroll
                    for (int nj = 0; nj < 8; ++nj)
                        acc[mi][nj] = fmaf(a[mi], bb[nj], acc[mi][nj]);
            }
            __syncthreads();
        }
        // epilogue: scale to cosine, insert into top-2
#pragma unroll
        for (int mi = 0; mi < 8; ++mi) {
            float im = invm[tm * 8 + mi];
#pragma unroll
            for (int nj = 0; nj < 8; ++nj) {
                int jl = (nj < 4) ? (tn * 4 + nj) : (256 + tn * 4 + nj - 4);
                float v = acc[mi][nj] * im * invc[jl];
                int n = nbase + nt + jl;
                if (v > v1[mi] || (v == v1[mi] && n < i1[mi])) {
                    v2[mi] = v1[mi]; i2[mi] = i1[mi]; v1[mi] = v; i1[mi] = n;
                } else if (v > v2[mi] || (v == v2[mi] && n < i2[mi])) {
                    v2[mi] = v; i2[mi] = n;
                }
            }
        }
    }

    // wave butterfly top-2 reduction (each wave == one tm, covers 8 m's)
#pragma unroll
    for (int mi = 0; mi < 8; ++mi) {
        float a1v = v1[mi], a2v = v2[mi]; int a1i = i1[mi], a2i = i2[mi];
        for (int off = 32; off; off >>= 1) {
            float o1v = __shfl_xor(a1v, off, 64); int o1i = __shfl_xor(a1i, off, 64);
            float o2v = __shfl_xor(a2v, off, 64); int o2i = __shfl_xor(a2i, off, 64);
            if (o1v > a1v || (o1v == a1v && o1i < a1i)) { a2v = a1v; a2i = a1i; a1v = o1v; a1i = o1i; }
            else if (o1v > a2v || (o1v == a2v && o1i < a2i)) { a2v = o1v; a2i = o1i; }
            if (o2v > a1v || (o2v == a1v && o2i < a1i)) { a2v = a1v; a2i = a1i; a1v = o2v; a1i = o2i; }
            else if (o2v > a2v || (o2v == a2v && o2i < a2i)) { a2v = o2v; a2i = o2i; }
        }
        if (tn == 0) {
            int m = m0 + tm * 8 + mi;
            int id = (b << 10) + m;
            int o = id * 4 + split * 2;     // [id][split][rank]
            pmax[o + 0] = a1v; pidx[o + 0] = a1i;
            pmax[o + 1] = a2v; pidx[o + 1] = a2i;
        }
    }
}

// ---------------- K3: combine splits + fp64 re-check near-ties -------------
__global__ void k_combine(const float* __restrict__ x,
    const int* __restrict__ nm_idx, const int* __restrict__ m_idx,
    const float* __restrict__ pmax, const int* __restrict__ pidx,
    float* __restrict__ maxc, int* __restrict__ bestp)
{
    int id = blockIdx.x * 256 + threadIdx.x;     // 8192
    int b = id >> 10, m = id & 1023;
    float v1 = -3.402823466e38f, v2 = -3.402823466e38f;
    int i1 = 0x7fffffff, i2 = 0x7fffffff;
#pragma unroll
    for (int r = 0; r < 4; ++r) {
        float v = pmax[id * 4 + r];
        int   n = pidx[id * 4 + r];
        if (v > v1 || (v == v1 && n < i1)) { v2 = v1; i2 = i1; v1 = v; i1 = n; }
        else if (v > v2 || (v == v2 && n < i2)) { v2 = v; i2 = n; }
    }
    if (v1 - v2 < 1e-5f) {
        // exact fp64 decision between the two candidates
        const float* xb = x + (size_t)b * C_ * HW_;
        int pm = m_idx[m], p1 = nm_idx[i1], p2 = nm_idx[i2];
        double smm = 0, s11 = 0, s22 = 0, sm1 = 0, sm2 = 0;
        for (int c = 0; c < C_; ++c) {
            double xm = xb[(size_t)c * HW_ + pm];
            double xa = xb[(size_t)c * HW_ + p1];
            double xc = xb[(size_t)c * HW_ + p2];
            smm += xm * xm; s11 += xa * xa; s22 += xc * xc;
            sm1 += xm * xa; sm2 += xm * xc;
        }
        double inv_m = 1.0 / (sqrt(smm) + 1e-8);
        double c1 = sm1 * inv_m / (sqrt(s11) + 1e-8);
        double c2 = sm2 * inv_m / (sqrt(s22) + 1e-8);
        if (c2 > c1 || (c2 == c1 && i2 < i1)) { v1 = v2; i1 = i2; }
    }
    maxc[id]  = v1;
    bestp[id] = nm_idx[i1];
}

// ---------------- K4: copy input -> output (context passthrough) -----------
__global__ void k_copy(const float4* __restrict__ in, float4* __restrict__ out) {
    int idx = blockIdx.x * 256 + threadIdx.x;
    int stride = gridDim.x * 256;
    for (int i = idx; i < (B_ * C_ * HW_ / 4); i += stride) out[i] = in[i];
}

// ---------------- K5: gather dense msk_n and best buffers ------------------
// grid = 256 blocks: b(8) x hole-row(32); block = 256 threads
__global__ __launch_bounds__(256) void k_gather(const float* __restrict__ x,
    const int* __restrict__ m_idx, const float* __restrict__ inv_all,
    const int* __restrict__ bestp, float* __restrict__ mskn, float* __restrict__ best)
{
    __shared__ float T[32][513];
    __shared__ int ps[32]; __shared__ float invm[32]; __shared__ int bp[32];
    int blk = blockIdx.x;
    int b = blk >> 5, row = blk & 31;
    int m0 = row * 32;
    int t = threadIdx.x;
    const float* xb = x + (size_t)b * C_ * HW_;
    if (t < 32) {
        int p = m_idx[m0 + t];
        ps[t] = p; invm[t] = inv_all[b * HW_ + p];
        bp[t] = bestp[(b << 10) + m0 + t];
    }
    __syncthreads();
    // transpose-load mask features: x[b][c][p_i] -> T[i][c]
#pragma unroll 4
    for (int rep = 0; rep < 64; ++rep) {
        int idx = rep * 256 + t;
        int c = idx >> 5, i = idx & 31;
        T[i][c] = xb[(size_t)c * HW_ + ps[i]];
    }
    __syncthreads();
#pragma unroll 4
    for (int rep = 0; rep < 64; ++rep) {
        int idx = rep * 256 + t;
        int i = idx >> 9, c = idx & 511;
        mskn[((size_t)(b << 10) + m0 + i) * C_ + c] = T[i][c] * invm[i];
    }
    // best: scattered reads, coalesced writes
    for (int mi = 0; mi < 32; ++mi) {
        int p = bp[mi];
        size_t o = ((size_t)(b << 10) + m0 + mi) * C_;
        for (int c = t; c < C_; c += 256)
            best[o + c] = xb[(size_t)c * HW_ + p];
    }
}

// ---------------- K6: sequential coherent scan (1 wave per batch) ----------
__global__ __launch_bounds__(64, 1) void k_scan(const float* __restrict__ mskn,
    const float* __restrict__ best, const float* __restrict__ maxc,
    const int* __restrict__ m_idx, float* __restrict__ out)
{
    int b = blockIdx.x;
    int lane = threadIdx.x;
    const float4* mn4 = (const float4*)(mskn + (size_t)b * M_ * C_);
    const float4* bs4 = (const float4*)(best + (size_t)b * M_ * C_);
    const float* mx_p = maxc + b * M_;
    float* outb = out + (size_t)b * C_ * HW_;

    float pr[8];
#pragma unroll
    for (int j = 0; j < 8; ++j) pr[j] = 0.f;

    // prefetch m=0
    float4 mA0 = mn4[lane * 2], mA1 = mn4[lane * 2 + 1];
    float4 bA0 = bs4[lane * 2], bA1 = bs4[lane * 2 + 1];
    float mxA = mx_p[0];
    int colA = m_idx[0];

    for (int m = 0; m < M_; ++m) {
        float4 mB0 = {0,0,0,0}, mB1 = {0,0,0,0}, bB0 = {0,0,0,0}, bB1 = {0,0,0,0};
        float mxB = 0.f; int colB = 0;
        if (m + 1 < M_) {
            int base = (m + 1) * 128 + lane * 2;
            mB0 = mn4[base]; mB1 = mn4[base + 1];
            bB0 = bs4[base]; bB1 = bs4[base + 1];
            mxB = mx_p[m + 1];
            colB = m_idx[m + 1];
        }
        float mn[8] = {mA0.x, mA0.y, mA0.z, mA0.w, mA1.x, mA1.y, mA1.z, mA1.w};
        float bs[8] = {bA0.x, bA0.y, bA0.z, bA0.w, bA1.x, bA1.y, bA1.z, bA1.w};
        float s1 = 0.f, s2 = 0.f;
#pragma unroll
        for (int j = 0; j < 8; ++j) {
            s1 = fmaf(pr[j], pr[j], s1);
            s2 = fmaf(mn[j], pr[j], s2);
        }
#pragma unroll
        for (int off = 32; off; off >>= 1) {
            s1 += __shfl_xor(s1, off, 64);
            s2 += __shfl_xor(s2, off, 64);
        }
        float norm = sqrtf(s1);
        float d_ad = fmaxf(s2, 0.f) / (norm + EPS_);
        float inv = 1.0f / (d_ad + mxA + EPS_);
#pragma unroll
        for (int j = 0; j < 8; ++j) {
            pr[j] = (d_ad * pr[j] + mxA * bs[j]) * inv;
            outb[(size_t)(lane * 8 + j) * HW_ + colA] = pr[j];
        }
        mA0 = mB0; mA1 = mB1; bA0 = bB0; bA1 = bB1; mxA = mxB; colA = colB;
    }
}

// ---------------- launch ----------------------------------------------------
extern "C" void kernel_launch(void* const* d_in, const int* in_sizes, int n_in,
                              void* d_out, int out_size, void* d_ws, size_t ws_size,
                              hipStream_t stream) {
    (void)in_sizes; (void)n_in; (void)out_size; (void)ws_size;
    const float* x      = (const float*)d_in[0];
    const int*   nm_idx = (const int*)d_in[2];
    const int*   m_idx  = (const int*)d_in[3];
    float* out = (float*)d_out;
    char* ws = (char*)d_ws;

    float* inv_all = (float*)(ws + 0);          // 131072 B
    float* pmax    = (float*)(ws + 131072);     // 131072 B  [8192][2 split][2 rank]
    int*   pidx    = (int*)  (ws + 262144);     // 131072 B
    float* maxc    = (float*)(ws + 393216);     // 32768 B
    int*   bestp   = (int*)  (ws + 425984);     // 32768 B
    float* mskn    = (float*)(ws + 458752);     // 16 MB
    float* best    = (float*)(ws + 17235968);   // 16 MB  (end ~33.4 MB)

    hipLaunchKernelGGL(k_norms,   dim3(256),  dim3(128), 0, stream, x, inv_all);
    hipLaunchKernelGGL(k_cos,     dim3(512),  dim3(256), 0, stream, x, nm_idx, m_idx, inv_all, pmax, pidx);
    hipLaunchKernelGGL(k_combine, dim3(32),   dim3(256), 0, stream, x, nm_idx, m_idx, pmax, pidx, maxc, bestp);
    hipLaunchKernelGGL(k_copy,    dim3(2048), dim3(256), 0, stream, (const float4*)x, (float4*)out);
    hipLaunchKernelGGL(k_gather,  dim3(256),  dim3(256), 0, stream, x, m_idx, inv_all, bestp, mskn, best);
    hipLaunchKernelGGL(k_scan,    dim3(8),    dim3(64),  0, stream, mskn, best, maxc, m_idx, out);
}